// Round 2
// baseline (1777.462 us; speedup 1.0000x reference)
//
#include <hip/hip_runtime.h>
#include <hip/hip_bf16.h>

#define NI 784
#define NH 1024
#define NO 10
#define BATCH 512
#define TSTEPS 100

#define BM 128
#define BN 128
#define BK 16
#define LDT 132   // LDS row stride in floats; (skcol)*132+srow -> 2-way writes (free)
#define TCH 10    // timesteps per cur2 block

typedef __attribute__((ext_vector_type(4))) float floatx4;

__global__ __launch_bounds__(256) void init_ws_kernel(float* __restrict__ p, int n) {
  int i = blockIdx.x * 256 + threadIdx.x;
  if (i < n) p[i] = 0.0f;
}

// C[M,1024] = X[M,784] @ W1[1024,784]^T + b1, fp32.
// 128x128 tile, BK=16, 256 threads, 8x8 micro-tile.
// Double-buffered LDS: ONE __syncthreads per K-tile (was two).
// XCD-contiguous block remap: hw-linear id h -> f=(h%8)*chunk+h/8 so each XCD
// owns a contiguous m-stripe x all 8 n-blocks (W1 3.2MB fits its 4MB L2).
// K-accumulation strictly sequential fmaf -> bit-identical to prior rounds.
__global__ __launch_bounds__(256) void sgemm1_kernel(
    const float* __restrict__ X,
    const float* __restrict__ W1,
    const float* __restrict__ b1,
    float* __restrict__ C)
{
  __shared__ __align__(16) float As[2][BK * LDT];
  __shared__ __align__(16) float Bs[2][BK * LDT];

  const int tid = threadIdx.x;
  const int tx = tid & 15;            // n-direction group (0..15)
  const int ty = tid >> 4;            // m-direction group (0..15)

  // bijective XCD-aware remap (gridDim.x==8 always; total = 32*tc, %8==0)
  const int hb    = blockIdx.y * gridDim.x + blockIdx.x;
  const int chunk = (gridDim.x * gridDim.y) >> 3;
  const int f     = (hb & 7) * chunk + (hb >> 3);
  const int n0 = (f & 7) * BN;
  const int m0 = (f >> 3) * BM;

  const int srow  = tid >> 2;         // 0..63 staging row
  const int skcol = (tid & 3) * 4;    // 0,4,8,12 staging k-offset

  float acc[8][8];
#pragma unroll
  for (int i = 0; i < 8; ++i)
#pragma unroll
    for (int j = 0; j < 8; ++j) acc[i][j] = 0.0f;

  const float* Xs  = X  + (size_t)m0 * NI + skcol;
  const float* W1s = W1 + (size_t)n0 * NI + skcol;

  // prefetch tile 0 into registers and stage into buffer 0
  floatx4 xa0 = *(const floatx4*)&Xs [(size_t)(srow)      * NI];
  floatx4 xa1 = *(const floatx4*)&Xs [(size_t)(64 + srow) * NI];
  floatx4 wq0 = *(const floatx4*)&W1s[(size_t)(srow)      * NI];
  floatx4 wq1 = *(const floatx4*)&W1s[(size_t)(64 + srow) * NI];

#pragma unroll
  for (int e = 0; e < 4; ++e) {
    As[0][(skcol + e) * LDT + srow]      = xa0[e];
    As[0][(skcol + e) * LDT + 64 + srow] = xa1[e];
    Bs[0][(skcol + e) * LDT + srow]      = wq0[e];
    Bs[0][(skcol + e) * LDT + 64 + srow] = wq1[e];
  }
  __syncthreads();

  const int NKT = NI / BK;            // 49
  for (int kt = 0; kt < NKT; ++kt) {
    const int cur = kt & 1;

    if (kt + 1 < NKT) {               // issue next tile's global loads early
      const int k0 = (kt + 1) * BK;
      xa0 = *(const floatx4*)&Xs [(size_t)(srow)      * NI + k0];
      xa1 = *(const floatx4*)&Xs [(size_t)(64 + srow) * NI + k0];
      wq0 = *(const floatx4*)&W1s[(size_t)(srow)      * NI + k0];
      wq1 = *(const floatx4*)&W1s[(size_t)(64 + srow) * NI + k0];
    }

#pragma unroll
    for (int k = 0; k < BK; ++k) {
      const floatx4 av0 = *(const floatx4*)&As[cur][k * LDT + ty * 8];
      const floatx4 av1 = *(const floatx4*)&As[cur][k * LDT + ty * 8 + 4];
      const floatx4 bv0 = *(const floatx4*)&Bs[cur][k * LDT + tx * 4];
      const floatx4 bv1 = *(const floatx4*)&Bs[cur][k * LDT + 64 + tx * 4];
      const float a[8] = {av0[0], av0[1], av0[2], av0[3],
                          av1[0], av1[1], av1[2], av1[3]};
#pragma unroll
      for (int i = 0; i < 8; ++i)
#pragma unroll
        for (int j = 0; j < 4; ++j) {
          acc[i][j]     = fmaf(a[i], bv0[j], acc[i][j]);
          acc[i][4 + j] = fmaf(a[i], bv1[j], acc[i][4 + j]);
        }
    }

    if (kt + 1 < NKT) {               // stage next tile into the other buffer
#pragma unroll
      for (int e = 0; e < 4; ++e) {
        As[cur ^ 1][(skcol + e) * LDT + srow]      = xa0[e];
        As[cur ^ 1][(skcol + e) * LDT + 64 + srow] = xa1[e];
        Bs[cur ^ 1][(skcol + e) * LDT + srow]      = wq0[e];
        Bs[cur ^ 1][(skcol + e) * LDT + 64 + srow] = wq1[e];
      }
    }
    __syncthreads();                  // single rendezvous per K-tile
  }

#pragma unroll
  for (int i = 0; i < 8; ++i) {
    const int m = m0 + ty * 8 + i;
    floatx4 v0, v1;
#pragma unroll
    for (int j = 0; j < 4; ++j) {
      v0[j] = acc[i][j]     + b1[n0 + tx * 4 + j];
      v1[j] = acc[i][4 + j] + b1[n0 + 64 + tx * 4 + j];
    }
    *(floatx4*)&C[(size_t)m * NH + n0 + tx * 4]      = v0;
    *(floatx4*)&C[(size_t)m * NH + n0 + 64 + tx * 4] = v1;
  }
}

// Phase A: elementwise mem1 recurrence, fully parallel over (b, h).
// One wave per (b, h-quarter); lane l owns h = qq*256 + 4l + j.
// Spikes bitpacked via __ballot: u64 pack[t][b][4 group][4 j].
// m1 update arithmetic copied verbatim from the proven recur kernel.
__global__ __launch_bounds__(64) void spk1_kernel(
    const float* __restrict__ cur1,
    unsigned long long* __restrict__ spk)
{
  const int b  = blockIdx.x;          // 0..511
  const int qq = blockIdx.y;          // 0..3  (h-quarter == pack group)
  const int l  = threadIdx.x;         // 0..63

  const floatx4* c4 = (const floatx4*)cur1;
  const size_t stride = (size_t)BATCH * (NH / 4);
  const size_t base   = (size_t)b * (NH / 4) + qq * 64 + l;

  floatx4 m1 = {0.f, 0.f, 0.f, 0.f};
  floatx4 c  = c4[base];

  for (int t = 0; t < TSTEPS; ++t) {
    floatx4 cn = {0.f, 0.f, 0.f, 0.f};
    if (t + 1 < TSTEPS) cn = c4[base + (size_t)(t + 1) * stride];

    unsigned long long bm0 = 0, bm1 = 0, bm2 = 0, bm3 = 0;
#pragma unroll
    for (int j = 0; j < 4; ++j) {
      float mj = m1[j];
      float reset = (mj > 1.0f) ? 1.0f : 0.0f;   // reset from PREVIOUS mem1
      mj = 0.9f * mj + c[j] - reset;
      m1[j] = mj;
      unsigned long long bm = __ballot(mj > 1.0f);
      if (j == 0) bm0 = bm; else if (j == 1) bm1 = bm;
      else if (j == 2) bm2 = bm; else bm3 = bm;
    }

    if (l < 4) {
      unsigned long long v = bm0;
      if (l == 1) v = bm1;
      else if (l == 2) v = bm2;
      else if (l == 3) v = bm3;
      spk[((size_t)t * BATCH + b) * 16 + qq * 4 + l] = v;
    }
    c = cn;
  }
}

// Phase B: cur2[t,b,o] for ALL t in parallel (grid 512 x 10 blocks).
// Thread tid owns the same h = tid*4+j as the old recur kernel; identical
// fmaf accumulation order, identical shfl_xor tree, identical red[] sum
// -> bit-identical cur2. Output transposed [b][o][t] for phase C.
__global__ __launch_bounds__(256) void cur2_kernel(
    const unsigned long long* __restrict__ spk,
    const float* __restrict__ W2,
    const float* __restrict__ b2,
    float* __restrict__ cur2T)
{
  const int b   = blockIdx.x;
  const int t0  = blockIdx.y * TCH;
  const int tid = threadIdx.x;
  const int lane = tid & 63;
  const int wave = tid >> 6;          // == pack group of this thread's h range

  __shared__ float red[2][4][NO];

  float w[4][NO];
#pragma unroll
  for (int j = 0; j < 4; ++j)
#pragma unroll
    for (int o = 0; o < NO; ++o)
      w[j][o] = W2[o * NH + tid * 4 + j];

  float bb = 0.0f;
  if (tid < NO) bb = b2[tid];

  for (int t = t0; t < t0 + TCH; ++t) {
    const unsigned long long* pk = spk + ((size_t)t * BATCH + b) * 16 + wave * 4;
    const unsigned long long p0 = pk[0], p1 = pk[1], p2 = pk[2], p3 = pk[3];

    float a[NO];
#pragma unroll
    for (int o = 0; o < NO; ++o) a[o] = 0.0f;

    {
      const float s0 = (float)((p0 >> lane) & 1ULL);
#pragma unroll
      for (int o = 0; o < NO; ++o) a[o] = fmaf(s0, w[0][o], a[o]);
      const float s1 = (float)((p1 >> lane) & 1ULL);
#pragma unroll
      for (int o = 0; o < NO; ++o) a[o] = fmaf(s1, w[1][o], a[o]);
      const float s2 = (float)((p2 >> lane) & 1ULL);
#pragma unroll
      for (int o = 0; o < NO; ++o) a[o] = fmaf(s2, w[2][o], a[o]);
      const float s3 = (float)((p3 >> lane) & 1ULL);
#pragma unroll
      for (int o = 0; o < NO; ++o) a[o] = fmaf(s3, w[3][o], a[o]);
    }

#pragma unroll
    for (int m = 1; m <= 32; m <<= 1)
#pragma unroll
      for (int o = 0; o < NO; ++o) a[o] += __shfl_xor(a[o], m, 64);

    if (lane == 0) {
#pragma unroll
      for (int o = 0; o < NO; ++o) red[t & 1][wave][o] = a[o];
    }
    __syncthreads();                  // parity buffers -> one barrier per t

    if (tid < NO) {
      float cur2 = red[t & 1][0][tid] + red[t & 1][1][tid]
                 + red[t & 1][2][tid] + red[t & 1][3][tid] + bb;
      cur2T[((size_t)b * NO + tid) * TSTEPS + t] = cur2;
    }
  }
}

// Phase C: mem2 recurrence — 5120 independent threads, t-serial but trivial.
// Fully unrolled so the 25 float4 loads hoist ahead of the recurrence chain.
__global__ __launch_bounds__(256) void mem2_kernel(
    const float* __restrict__ cur2T,
    float* __restrict__ out,
    long long out_size)
{
  const int id = blockIdx.x * 256 + threadIdx.x;
  if (id >= BATCH * NO) return;
  const int b = id / NO;
  const int o = id % NO;
  const float* row = cur2T + (size_t)id * TSTEPS;   // id == b*NO+o

  float m2 = 0.0f;
#pragma unroll
  for (int t = 0; t < TSTEPS; t += 4) {
    const floatx4 v = *(const floatx4*)&row[t];
#pragma unroll
    for (int e = 0; e < 4; ++e) {
      float reset2 = (m2 > 1.0f) ? 1.0f : 0.0f;
      m2 = 0.9f * m2 + v[e] - reset2;
      float spk2 = (m2 > 1.0f) ? 1.0f : 0.0f;
      long long idx = ((long long)(t + e) * BATCH + b) * NO + o;
      if (idx < out_size) out[idx] = spk2;
    }
  }
  long long idx = (long long)TSTEPS * BATCH * NO + id;
  if (idx < out_size) out[idx] = m2;
}

// Proven fallback recur (chunked path, used only if ws too small for phases).
__global__ __launch_bounds__(256) void recur_kernel(
    const float* __restrict__ cur1,
    const float* __restrict__ W2,
    const float* __restrict__ b2,
    float* __restrict__ mem1s,
    float* __restrict__ mem2s,
    float* __restrict__ out,
    long long out_size, int t0, int tc, int last)
{
  const int b    = blockIdx.x;
  const int tid  = threadIdx.x;
  const int lane = tid & 63;
  const int wave = tid >> 6;

  __shared__ float red[4][NO];

  float w[4][NO];
#pragma unroll
  for (int j = 0; j < 4; ++j)
#pragma unroll
    for (int o = 0; o < NO; ++o)
      w[j][o] = W2[o * NH + tid * 4 + j];

  floatx4 m1 = *(const floatx4*)&mem1s[(size_t)b * NH + tid * 4];
  float m2 = 0.0f, bb = 0.0f;
  if (tid < NO) {
    m2 = mem2s[b * NO + tid];
    bb = b2[tid];
  }

  const floatx4* c4 = (const floatx4*)cur1;
  floatx4 c = c4[((size_t)0 * BATCH + b) * (NH / 4) + tid];

  for (int t = 0; t < tc; ++t) {
    floatx4 cn = {0.f, 0.f, 0.f, 0.f};
    if (t + 1 < tc) cn = c4[((size_t)(t + 1) * BATCH + b) * (NH / 4) + tid];

    float a[NO];
#pragma unroll
    for (int o = 0; o < NO; ++o) a[o] = 0.0f;

#pragma unroll
    for (int j = 0; j < 4; ++j) {
      float mj = m1[j];
      float reset = (mj > 1.0f) ? 1.0f : 0.0f;
      mj = 0.9f * mj + c[j] - reset;
      m1[j] = mj;
      float s = (mj > 1.0f) ? 1.0f : 0.0f;
#pragma unroll
      for (int o = 0; o < NO; ++o) a[o] = fmaf(s, w[j][o], a[o]);
    }

#pragma unroll
    for (int m = 1; m <= 32; m <<= 1)
#pragma unroll
      for (int o = 0; o < NO; ++o) a[o] += __shfl_xor(a[o], m, 64);

    if (lane == 0) {
#pragma unroll
      for (int o = 0; o < NO; ++o) red[wave][o] = a[o];
    }
    __syncthreads();

    if (tid < NO) {
      float cur2 = red[0][tid] + red[1][tid] + red[2][tid] + red[3][tid] + bb;
      float reset2 = (m2 > 1.0f) ? 1.0f : 0.0f;
      m2 = 0.9f * m2 + cur2 - reset2;
      float spk2 = (m2 > 1.0f) ? 1.0f : 0.0f;
      long long idx = ((long long)(t0 + t) * BATCH + b) * NO + tid;
      if (idx < out_size) out[idx] = spk2;
    }
    __syncthreads();
    c = cn;
  }

  *(floatx4*)&mem1s[(size_t)b * NH + tid * 4] = m1;
  if (tid < NO) {
    mem2s[b * NO + tid] = m2;
    if (last) {
      long long idx = (long long)TSTEPS * BATCH * NO + b * NO + tid;
      if (idx < out_size) out[idx] = m2;
    }
  }
}

// Proven round-3 fallback (only if workspace is too small for any GEMM path).
__global__ __launch_bounds__(256) void fused_fp32_kernel(
    const float* __restrict__ x,
    const float* __restrict__ W1,
    const float* __restrict__ b1,
    const float* __restrict__ W2,
    const float* __restrict__ b2,
    float* __restrict__ out, long long out_size)
{
  const int b    = blockIdx.x;
  const int tid  = threadIdx.x;
  const int lane = tid & 63;
  const int wave = tid >> 6;

  __shared__ __align__(16) float xs[NI + 4];
  __shared__ float red[4][NO];

  float w[4][NO];
#pragma unroll
  for (int j = 0; j < 4; ++j)
#pragma unroll
    for (int o = 0; o < NO; ++o)
      w[j][o] = W2[o * NH + tid * 4 + j];

  float bias1[4];
#pragma unroll
  for (int j = 0; j < 4; ++j) bias1[j] = b1[tid * 4 + j];

  float m1[4] = {0.f, 0.f, 0.f, 0.f};
  float m2 = 0.0f, bb = 0.0f;
  if (tid < NO) bb = b2[tid];

  for (int t = 0; t < TSTEPS; ++t) {
    if (tid < 196)
      *(floatx4*)&xs[tid * 4] = *(const floatx4*)&x[((size_t)t * BATCH + b) * NI + tid * 4];
    __syncthreads();

    float a[NO];
#pragma unroll
    for (int o = 0; o < NO; ++o) a[o] = 0.0f;

#pragma unroll
    for (int j = 0; j < 4; ++j) {
      const float* wr = W1 + (size_t)(tid * 4 + j) * NI;
      float dot = 0.0f;
      for (int cch = 0; cch < 196; ++cch) {
        floatx4 wv = *(const floatx4*)&wr[cch * 4];
        floatx4 xv = *(const floatx4*)&xs[cch * 4];
#pragma unroll
        for (int e = 0; e < 4; ++e) dot = fmaf(wv[e], xv[e], dot);
      }
      float cur = dot + bias1[j];
      float mj = m1[j];
      float reset = (mj > 1.0f) ? 1.0f : 0.0f;
      mj = 0.9f * mj + cur - reset;
      m1[j] = mj;
      float s = (mj > 1.0f) ? 1.0f : 0.0f;
#pragma unroll
      for (int o = 0; o < NO; ++o) a[o] = fmaf(s, w[j][o], a[o]);
    }

#pragma unroll
    for (int m = 1; m <= 32; m <<= 1)
#pragma unroll
      for (int o = 0; o < NO; ++o) a[o] += __shfl_xor(a[o], m, 64);

    if (lane == 0) {
#pragma unroll
      for (int o = 0; o < NO; ++o) red[wave][o] = a[o];
    }
    __syncthreads();

    if (tid < NO) {
      float cur2 = red[0][tid] + red[1][tid] + red[2][tid] + red[3][tid] + bb;
      float reset2 = (m2 > 1.0f) ? 1.0f : 0.0f;
      m2 = 0.9f * m2 + cur2 - reset2;
      float spk2 = (m2 > 1.0f) ? 1.0f : 0.0f;
      long long idx = ((long long)t * BATCH + b) * NO + tid;
      if (idx < out_size) out[idx] = spk2;
    }
    __syncthreads();
  }

  if (tid < NO) {
    long long idx = (long long)TSTEPS * BATCH * NO + b * NO + tid;
    if (idx < out_size) out[idx] = m2;
  }
}

extern "C" void kernel_launch(void* const* d_in, const int* in_sizes, int n_in,
                              void* d_out, int out_size, void* d_ws, size_t ws_size,
                              hipStream_t stream) {
  const float* x  = (const float*)d_in[0];
  const float* W1 = (const float*)d_in[1];
  const float* b1 = (const float*)d_in[2];
  const float* W2 = (const float*)d_in[3];
  const float* b2 = (const float*)d_in[4];
  float* out = (float*)d_out;

  char* ws = (char*)d_ws;

  // ---------- preferred path: full-T GEMM + phase-split recurrence ----------
  // ws layout: [cur2T 2.048MB][cur1 200MB][spk1 bitpack 6.55MB]
  const size_t cur2T_bytes = (size_t)BATCH * NO * TSTEPS * 4;
  const size_t head        = (cur2T_bytes + 255) & ~(size_t)255;
  const size_t cur1_bytes  = (size_t)TSTEPS * BATCH * NH * 4;
  const size_t pack_bytes  = (size_t)TSTEPS * BATCH * 16 * 8;
  const size_t need_full   = head + cur1_bytes + pack_bytes;

  if (d_ws != nullptr && ws_size >= need_full) {
    float* cur2T = (float*)ws;
    float* cur1  = (float*)(ws + head);
    unsigned long long* spk = (unsigned long long*)(ws + head + cur1_bytes);

    dim3 g(NH / BN, (TSTEPS * BATCH) / BM);        // (8, 400)
    sgemm1_kernel<<<g, 256, 0, stream>>>(x, W1, b1, cur1);
    spk1_kernel<<<dim3(BATCH, 4), 64, 0, stream>>>(cur1, spk);
    cur2_kernel<<<dim3(BATCH, TSTEPS / TCH), 256, 0, stream>>>(spk, W2, b2, cur2T);
    mem2_kernel<<<(BATCH * NO + 255) / 256, 256, 0, stream>>>(cur2T, out,
                                                              (long long)out_size);
    return;
  }

  // ---------- fallback: proven chunked GEMM + recur path ----------
  const size_t mem1_bytes = (size_t)BATCH * NH * 4;
  const size_t mem2_bytes = (size_t)BATCH * NO * 4;
  size_t fixed = (mem1_bytes + mem2_bytes + 255) & ~(size_t)255;
  const size_t per_step = (size_t)BATCH * NH * 4;   // 2 MB fp32 per timestep

  if (d_ws == nullptr || ws_size < fixed + per_step) {
    fused_fp32_kernel<<<BATCH, 256, 0, stream>>>(x, W1, b1, W2, b2, out,
                                                 (long long)out_size);
    return;
  }

  float* mem1s = (float*)ws;
  float* mem2s = (float*)(ws + mem1_bytes);
  float* cur1  = (float*)(ws + fixed);

  int Tc = (int)((ws_size - fixed) / per_step);
  if (Tc > TSTEPS) Tc = TSTEPS;

  const int nInit = BATCH * NH + BATCH * NO;
  init_ws_kernel<<<(nInit + 255) / 256, 256, 0, stream>>>((float*)ws, nInit);

  for (int t0 = 0; t0 < TSTEPS; t0 += Tc) {
    const int tc = (TSTEPS - t0 < Tc) ? (TSTEPS - t0) : Tc;
    const int M = tc * BATCH;                    // multiple of 128
    dim3 g(NH / BN, M / BM);
    sgemm1_kernel<<<g, 256, 0, stream>>>(x + (size_t)t0 * BATCH * NI, W1, b1, cur1);
    recur_kernel<<<BATCH, 256, 0, stream>>>(cur1, W2, b2, mem1s, mem2s, out,
                                            (long long)out_size, t0, tc,
                                            (t0 + tc >= TSTEPS) ? 1 : 0);
  }
}

// Round 3
// 1316.565 us; speedup vs baseline: 1.3501x; 1.3501x over previous
//
#include <hip/hip_runtime.h>
#include <hip/hip_bf16.h>

#define NI 784
#define NH 1024
#define NO 10
#define BATCH 512
#define TSTEPS 100

#define BM 128
#define BN 128
#define BK 16
#define LDT 132   // LDS row stride in floats; (skcol)*132+srow -> 2-way writes (free)
#define TCH 10    // timesteps per cur2 block

typedef __attribute__((ext_vector_type(4))) float floatx4;

__global__ __launch_bounds__(256) void init_ws_kernel(float* __restrict__ p, int n) {
  int i = blockIdx.x * 256 + threadIdx.x;
  if (i < n) p[i] = 0.0f;
}

// C[M,1024] = X[M,784] @ W1[1024,784]^T + b1, fp32.
// ROUND-0 PROVEN STRUCTURE (single LDS buffer, 2 barriers/K-tile, register
// prefetch): 80 VGPR, 30% occupancy, 75% VALUBusy at 962us.
// + XCD-contiguous remap ONLY (round 2 proved it cuts FETCH 682->243MB with
// zero register cost: all 8 n-blocks of one m-stripe co-resident per XCD,
// W1 3.2MB lives in that XCD's 4MB L2).
// Round-2's double-buffer is REVERTED: it cost 184 VGPR -> 11% occupancy.
// K-accumulation strictly sequential fmaf -> bit-identical to prior rounds.
__global__ __launch_bounds__(256) void sgemm1_kernel(
    const float* __restrict__ X,
    const float* __restrict__ W1,
    const float* __restrict__ b1,
    float* __restrict__ C)
{
  __shared__ __align__(16) float As[BK * LDT];
  __shared__ __align__(16) float Bs[BK * LDT];

  const int tid = threadIdx.x;
  const int tx = tid & 15;            // n-direction group (0..15)
  const int ty = tid >> 4;            // m-direction group (0..15)

  // bijective XCD-aware remap (total blocks = 32*tc, always %8==0)
  const int hb    = blockIdx.y * gridDim.x + blockIdx.x;
  const int chunk = (gridDim.x * gridDim.y) >> 3;
  const int f     = (hb & 7) * chunk + (hb >> 3);
  const int n0 = (f & 7) * BN;
  const int m0 = (f >> 3) * BM;

  const int srow  = tid >> 2;         // 0..63 staging row
  const int skcol = (tid & 3) * 4;    // 0,4,8,12 staging k-offset

  float acc[8][8];
#pragma unroll
  for (int i = 0; i < 8; ++i)
#pragma unroll
    for (int j = 0; j < 8; ++j) acc[i][j] = 0.0f;

  const float* Xs  = X  + (size_t)m0 * NI + skcol;
  const float* W1s = W1 + (size_t)n0 * NI + skcol;

  // prefetch tile 0 into registers
  floatx4 xa0 = *(const floatx4*)&Xs [(size_t)(srow)      * NI];
  floatx4 xa1 = *(const floatx4*)&Xs [(size_t)(64 + srow) * NI];
  floatx4 wq0 = *(const floatx4*)&W1s[(size_t)(srow)      * NI];
  floatx4 wq1 = *(const floatx4*)&W1s[(size_t)(64 + srow) * NI];

  for (int kt = 0; kt < NI / BK; ++kt) {
    __syncthreads();                  // previous tile fully consumed
#pragma unroll
    for (int e = 0; e < 4; ++e) {
      As[(skcol + e) * LDT + srow]      = xa0[e];
      As[(skcol + e) * LDT + 64 + srow] = xa1[e];
      Bs[(skcol + e) * LDT + srow]      = wq0[e];
      Bs[(skcol + e) * LDT + 64 + srow] = wq1[e];
    }
    __syncthreads();

    if (kt + 1 < NI / BK) {           // prefetch next tile; overlaps compute
      const int k0 = (kt + 1) * BK;
      xa0 = *(const floatx4*)&Xs [(size_t)(srow)      * NI + k0];
      xa1 = *(const floatx4*)&Xs [(size_t)(64 + srow) * NI + k0];
      wq0 = *(const floatx4*)&W1s[(size_t)(srow)      * NI + k0];
      wq1 = *(const floatx4*)&W1s[(size_t)(64 + srow) * NI + k0];
    }

#pragma unroll
    for (int k = 0; k < BK; ++k) {
      const floatx4 av0 = *(const floatx4*)&As[k * LDT + ty * 8];
      const floatx4 av1 = *(const floatx4*)&As[k * LDT + ty * 8 + 4];
      const floatx4 bv0 = *(const floatx4*)&Bs[k * LDT + tx * 4];        // 2-way, free
      const floatx4 bv1 = *(const floatx4*)&Bs[k * LDT + 64 + tx * 4];   // 2-way, free
      const float a[8] = {av0[0], av0[1], av0[2], av0[3],
                          av1[0], av1[1], av1[2], av1[3]};
#pragma unroll
      for (int i = 0; i < 8; ++i)
#pragma unroll
        for (int j = 0; j < 4; ++j) {
          acc[i][j]     = fmaf(a[i], bv0[j], acc[i][j]);
          acc[i][4 + j] = fmaf(a[i], bv1[j], acc[i][4 + j]);
        }
    }
  }

#pragma unroll
  for (int i = 0; i < 8; ++i) {
    const int m = m0 + ty * 8 + i;
    floatx4 v0, v1;
#pragma unroll
    for (int j = 0; j < 4; ++j) {
      v0[j] = acc[i][j]     + b1[n0 + tx * 4 + j];
      v1[j] = acc[i][4 + j] + b1[n0 + 64 + tx * 4 + j];
    }
    *(floatx4*)&C[(size_t)m * NH + n0 + tx * 4]      = v0;
    *(floatx4*)&C[(size_t)m * NH + n0 + 64 + tx * 4] = v1;
  }
}

// Phase A: elementwise mem1 recurrence, fully parallel over (b, h).
// One wave per (b, h-quarter); lane l owns h = qq*256 + 4l + j.
// Depth-2 prefetch: load for t+2 issued at iter t -> per-iter stall ~halved.
// Spikes bitpacked via __ballot: u64 pack[t][b][4 group][4 j].
// m1 update arithmetic copied verbatim from the proven recur kernel.
__global__ __launch_bounds__(64) void spk1_kernel(
    const float* __restrict__ cur1,
    unsigned long long* __restrict__ spk)
{
  const int b  = blockIdx.x;          // 0..511
  const int qq = blockIdx.y;          // 0..3  (h-quarter == pack group)
  const int l  = threadIdx.x;         // 0..63

  const floatx4* c4 = (const floatx4*)cur1;
  const size_t stride = (size_t)BATCH * (NH / 4);
  const size_t base   = (size_t)b * (NH / 4) + qq * 64 + l;

  floatx4 m1 = {0.f, 0.f, 0.f, 0.f};
  floatx4 c  = c4[base];
  floatx4 c1 = c4[base + stride];     // TSTEPS >= 2 always

  for (int t = 0; t < TSTEPS; ++t) {
    floatx4 c2 = {0.f, 0.f, 0.f, 0.f};
    if (t + 2 < TSTEPS) c2 = c4[base + (size_t)(t + 2) * stride];

    unsigned long long bm0 = 0, bm1 = 0, bm2 = 0, bm3 = 0;
#pragma unroll
    for (int j = 0; j < 4; ++j) {
      float mj = m1[j];
      float reset = (mj > 1.0f) ? 1.0f : 0.0f;   // reset from PREVIOUS mem1
      mj = 0.9f * mj + c[j] - reset;
      m1[j] = mj;
      unsigned long long bm = __ballot(mj > 1.0f);
      if (j == 0) bm0 = bm; else if (j == 1) bm1 = bm;
      else if (j == 2) bm2 = bm; else bm3 = bm;
    }

    if (l < 4) {
      unsigned long long v = bm0;
      if (l == 1) v = bm1;
      else if (l == 2) v = bm2;
      else if (l == 3) v = bm3;
      spk[((size_t)t * BATCH + b) * 16 + qq * 4 + l] = v;
    }
    c = c1; c1 = c2;
  }
}

// Phase B: cur2[t,b,o] for ALL t in parallel (grid 512 x 10 blocks).
// Thread tid owns the same h = tid*4+j as the old recur kernel; identical
// fmaf accumulation order, identical shfl_xor tree, identical red[] sum
// -> bit-identical cur2. Output transposed [b][o][t] for phase C.
__global__ __launch_bounds__(256) void cur2_kernel(
    const unsigned long long* __restrict__ spk,
    const float* __restrict__ W2,
    const float* __restrict__ b2,
    float* __restrict__ cur2T)
{
  const int b   = blockIdx.x;
  const int t0  = blockIdx.y * TCH;
  const int tid = threadIdx.x;
  const int lane = tid & 63;
  const int wave = tid >> 6;          // == pack group of this thread's h range

  __shared__ float red[2][4][NO];

  float w[4][NO];
#pragma unroll
  for (int j = 0; j < 4; ++j)
#pragma unroll
    for (int o = 0; o < NO; ++o)
      w[j][o] = W2[o * NH + tid * 4 + j];

  float bb = 0.0f;
  if (tid < NO) bb = b2[tid];

  for (int t = t0; t < t0 + TCH; ++t) {
    const unsigned long long* pk = spk + ((size_t)t * BATCH + b) * 16 + wave * 4;
    const unsigned long long p0 = pk[0], p1 = pk[1], p2 = pk[2], p3 = pk[3];

    float a[NO];
#pragma unroll
    for (int o = 0; o < NO; ++o) a[o] = 0.0f;

    {
      const float s0 = (float)((p0 >> lane) & 1ULL);
#pragma unroll
      for (int o = 0; o < NO; ++o) a[o] = fmaf(s0, w[0][o], a[o]);
      const float s1 = (float)((p1 >> lane) & 1ULL);
#pragma unroll
      for (int o = 0; o < NO; ++o) a[o] = fmaf(s1, w[1][o], a[o]);
      const float s2 = (float)((p2 >> lane) & 1ULL);
#pragma unroll
      for (int o = 0; o < NO; ++o) a[o] = fmaf(s2, w[2][o], a[o]);
      const float s3 = (float)((p3 >> lane) & 1ULL);
#pragma unroll
      for (int o = 0; o < NO; ++o) a[o] = fmaf(s3, w[3][o], a[o]);
    }

#pragma unroll
    for (int m = 1; m <= 32; m <<= 1)
#pragma unroll
      for (int o = 0; o < NO; ++o) a[o] += __shfl_xor(a[o], m, 64);

    if (lane == 0) {
#pragma unroll
      for (int o = 0; o < NO; ++o) red[t & 1][wave][o] = a[o];
    }
    __syncthreads();                  // parity buffers -> one barrier per t

    if (tid < NO) {
      float cur2 = red[t & 1][0][tid] + red[t & 1][1][tid]
                 + red[t & 1][2][tid] + red[t & 1][3][tid] + bb;
      cur2T[((size_t)b * NO + tid) * TSTEPS + t] = cur2;
    }
  }
}

// Phase C: mem2 recurrence — 5120 independent threads, t-serial but trivial.
// Fully unrolled so the 25 float4 loads hoist ahead of the recurrence chain.
__global__ __launch_bounds__(256) void mem2_kernel(
    const float* __restrict__ cur2T,
    float* __restrict__ out,
    long long out_size)
{
  const int id = blockIdx.x * 256 + threadIdx.x;
  if (id >= BATCH * NO) return;
  const int b = id / NO;
  const int o = id % NO;
  const float* row = cur2T + (size_t)id * TSTEPS;   // id == b*NO+o

  float m2 = 0.0f;
#pragma unroll
  for (int t = 0; t < TSTEPS; t += 4) {
    const floatx4 v = *(const floatx4*)&row[t];
#pragma unroll
    for (int e = 0; e < 4; ++e) {
      float reset2 = (m2 > 1.0f) ? 1.0f : 0.0f;
      m2 = 0.9f * m2 + v[e] - reset2;
      float spk2 = (m2 > 1.0f) ? 1.0f : 0.0f;
      long long idx = ((long long)(t + e) * BATCH + b) * NO + o;
      if (idx < out_size) out[idx] = spk2;
    }
  }
  long long idx = (long long)TSTEPS * BATCH * NO + id;
  if (idx < out_size) out[idx] = m2;
}

// Proven fallback recur (chunked path, used only if ws too small for phases).
__global__ __launch_bounds__(256) void recur_kernel(
    const float* __restrict__ cur1,
    const float* __restrict__ W2,
    const float* __restrict__ b2,
    float* __restrict__ mem1s,
    float* __restrict__ mem2s,
    float* __restrict__ out,
    long long out_size, int t0, int tc, int last)
{
  const int b    = blockIdx.x;
  const int tid  = threadIdx.x;
  const int lane = tid & 63;
  const int wave = tid >> 6;

  __shared__ float red[4][NO];

  float w[4][NO];
#pragma unroll
  for (int j = 0; j < 4; ++j)
#pragma unroll
    for (int o = 0; o < NO; ++o)
      w[j][o] = W2[o * NH + tid * 4 + j];

  floatx4 m1 = *(const floatx4*)&mem1s[(size_t)b * NH + tid * 4];
  float m2 = 0.0f, bb = 0.0f;
  if (tid < NO) {
    m2 = mem2s[b * NO + tid];
    bb = b2[tid];
  }

  const floatx4* c4 = (const floatx4*)cur1;
  floatx4 c = c4[((size_t)0 * BATCH + b) * (NH / 4) + tid];

  for (int t = 0; t < tc; ++t) {
    floatx4 cn = {0.f, 0.f, 0.f, 0.f};
    if (t + 1 < tc) cn = c4[((size_t)(t + 1) * BATCH + b) * (NH / 4) + tid];

    float a[NO];
#pragma unroll
    for (int o = 0; o < NO; ++o) a[o] = 0.0f;

#pragma unroll
    for (int j = 0; j < 4; ++j) {
      float mj = m1[j];
      float reset = (mj > 1.0f) ? 1.0f : 0.0f;
      mj = 0.9f * mj + c[j] - reset;
      m1[j] = mj;
      float s = (mj > 1.0f) ? 1.0f : 0.0f;
#pragma unroll
      for (int o = 0; o < NO; ++o) a[o] = fmaf(s, w[j][o], a[o]);
    }

#pragma unroll
    for (int m = 1; m <= 32; m <<= 1)
#pragma unroll
      for (int o = 0; o < NO; ++o) a[o] += __shfl_xor(a[o], m, 64);

    if (lane == 0) {
#pragma unroll
      for (int o = 0; o < NO; ++o) red[wave][o] = a[o];
    }
    __syncthreads();

    if (tid < NO) {
      float cur2 = red[0][tid] + red[1][tid] + red[2][tid] + red[3][tid] + bb;
      float reset2 = (m2 > 1.0f) ? 1.0f : 0.0f;
      m2 = 0.9f * m2 + cur2 - reset2;
      float spk2 = (m2 > 1.0f) ? 1.0f : 0.0f;
      long long idx = ((long long)(t0 + t) * BATCH + b) * NO + tid;
      if (idx < out_size) out[idx] = spk2;
    }
    __syncthreads();
    c = cn;
  }

  *(floatx4*)&mem1s[(size_t)b * NH + tid * 4] = m1;
  if (tid < NO) {
    mem2s[b * NO + tid] = m2;
    if (last) {
      long long idx = (long long)TSTEPS * BATCH * NO + b * NO + tid;
      if (idx < out_size) out[idx] = m2;
    }
  }
}

// Proven round-3 fallback (only if workspace is too small for any GEMM path).
__global__ __launch_bounds__(256) void fused_fp32_kernel(
    const float* __restrict__ x,
    const float* __restrict__ W1,
    const float* __restrict__ b1,
    const float* __restrict__ W2,
    const float* __restrict__ b2,
    float* __restrict__ out, long long out_size)
{
  const int b    = blockIdx.x;
  const int tid  = threadIdx.x;
  const int lane = tid & 63;
  const int wave = tid >> 6;

  __shared__ __align__(16) float xs[NI + 4];
  __shared__ float red[4][NO];

  float w[4][NO];
#pragma unroll
  for (int j = 0; j < 4; ++j)
#pragma unroll
    for (int o = 0; o < NO; ++o)
      w[j][o] = W2[o * NH + tid * 4 + j];

  float bias1[4];
#pragma unroll
  for (int j = 0; j < 4; ++j) bias1[j] = b1[tid * 4 + j];

  float m1[4] = {0.f, 0.f, 0.f, 0.f};
  float m2 = 0.0f, bb = 0.0f;
  if (tid < NO) bb = b2[tid];

  for (int t = 0; t < TSTEPS; ++t) {
    if (tid < 196)
      *(floatx4*)&xs[tid * 4] = *(const floatx4*)&x[((size_t)t * BATCH + b) * NI + tid * 4];
    __syncthreads();

    float a[NO];
#pragma unroll
    for (int o = 0; o < NO; ++o) a[o] = 0.0f;

#pragma unroll
    for (int j = 0; j < 4; ++j) {
      const float* wr = W1 + (size_t)(tid * 4 + j) * NI;
      float dot = 0.0f;
      for (int cch = 0; cch < 196; ++cch) {
        floatx4 wv = *(const floatx4*)&wr[cch * 4];
        floatx4 xv = *(const floatx4*)&xs[cch * 4];
#pragma unroll
        for (int e = 0; e < 4; ++e) dot = fmaf(wv[e], xv[e], dot);
      }
      float cur = dot + bias1[j];
      float mj = m1[j];
      float reset = (mj > 1.0f) ? 1.0f : 0.0f;
      mj = 0.9f * mj + cur - reset;
      m1[j] = mj;
      float s = (mj > 1.0f) ? 1.0f : 0.0f;
#pragma unroll
      for (int o = 0; o < NO; ++o) a[o] = fmaf(s, w[j][o], a[o]);
    }

#pragma unroll
    for (int m = 1; m <= 32; m <<= 1)
#pragma unroll
      for (int o = 0; o < NO; ++o) a[o] += __shfl_xor(a[o], m, 64);

    if (lane == 0) {
#pragma unroll
      for (int o = 0; o < NO; ++o) red[wave][o] = a[o];
    }
    __syncthreads();

    if (tid < NO) {
      float cur2 = red[0][tid] + red[1][tid] + red[2][tid] + red[3][tid] + bb;
      float reset2 = (m2 > 1.0f) ? 1.0f : 0.0f;
      m2 = 0.9f * m2 + cur2 - reset2;
      float spk2 = (m2 > 1.0f) ? 1.0f : 0.0f;
      long long idx = ((long long)t * BATCH + b) * NO + tid;
      if (idx < out_size) out[idx] = spk2;
    }
    __syncthreads();
  }

  if (tid < NO) {
    long long idx = (long long)TSTEPS * BATCH * NO + b * NO + tid;
    if (idx < out_size) out[idx] = m2;
  }
}

extern "C" void kernel_launch(void* const* d_in, const int* in_sizes, int n_in,
                              void* d_out, int out_size, void* d_ws, size_t ws_size,
                              hipStream_t stream) {
  const float* x  = (const float*)d_in[0];
  const float* W1 = (const float*)d_in[1];
  const float* b1 = (const float*)d_in[2];
  const float* W2 = (const float*)d_in[3];
  const float* b2 = (const float*)d_in[4];
  float* out = (float*)d_out;

  char* ws = (char*)d_ws;

  // ---------- preferred path: full-T GEMM + phase-split recurrence ----------
  // ws layout: [cur2T 2.048MB][cur1 200MB][spk1 bitpack 6.55MB]
  const size_t cur2T_bytes = (size_t)BATCH * NO * TSTEPS * 4;
  const size_t head        = (cur2T_bytes + 255) & ~(size_t)255;
  const size_t cur1_bytes  = (size_t)TSTEPS * BATCH * NH * 4;
  const size_t pack_bytes  = (size_t)TSTEPS * BATCH * 16 * 8;
  const size_t need_full   = head + cur1_bytes + pack_bytes;

  if (d_ws != nullptr && ws_size >= need_full) {
    float* cur2T = (float*)ws;
    float* cur1  = (float*)(ws + head);
    unsigned long long* spk = (unsigned long long*)(ws + head + cur1_bytes);

    dim3 g(NH / BN, (TSTEPS * BATCH) / BM);        // (8, 400)
    sgemm1_kernel<<<g, 256, 0, stream>>>(x, W1, b1, cur1);
    spk1_kernel<<<dim3(BATCH, 4), 64, 0, stream>>>(cur1, spk);
    cur2_kernel<<<dim3(BATCH, TSTEPS / TCH), 256, 0, stream>>>(spk, W2, b2, cur2T);
    mem2_kernel<<<(BATCH * NO + 255) / 256, 256, 0, stream>>>(cur2T, out,
                                                              (long long)out_size);
    return;
  }

  // ---------- fallback: proven chunked GEMM + recur path ----------
  const size_t mem1_bytes = (size_t)BATCH * NH * 4;
  const size_t mem2_bytes = (size_t)BATCH * NO * 4;
  size_t fixed = (mem1_bytes + mem2_bytes + 255) & ~(size_t)255;
  const size_t per_step = (size_t)BATCH * NH * 4;   // 2 MB fp32 per timestep

  if (d_ws == nullptr || ws_size < fixed + per_step) {
    fused_fp32_kernel<<<BATCH, 256, 0, stream>>>(x, W1, b1, W2, b2, out,
                                                 (long long)out_size);
    return;
  }

  float* mem1s = (float*)ws;
  float* mem2s = (float*)(ws + mem1_bytes);
  float* cur1  = (float*)(ws + fixed);

  int Tc = (int)((ws_size - fixed) / per_step);
  if (Tc > TSTEPS) Tc = TSTEPS;

  const int nInit = BATCH * NH + BATCH * NO;
  init_ws_kernel<<<(nInit + 255) / 256, 256, 0, stream>>>((float*)ws, nInit);

  for (int t0 = 0; t0 < TSTEPS; t0 += Tc) {
    const int tc = (TSTEPS - t0 < Tc) ? (TSTEPS - t0) : Tc;
    const int M = tc * BATCH;                    // multiple of 128
    dim3 g(NH / BN, M / BM);
    sgemm1_kernel<<<g, 256, 0, stream>>>(x + (size_t)t0 * BATCH * NI, W1, b1, cur1);
    recur_kernel<<<BATCH, 256, 0, stream>>>(cur1, W2, b2, mem1s, mem2s, out,
                                            (long long)out_size, t0, tc,
                                            (t0 + tc >= TSTEPS) ? 1 : 0);
  }
}

// Round 4
// 1280.194 us; speedup vs baseline: 1.3884x; 1.0284x over previous
//
#include <hip/hip_runtime.h>
#include <hip/hip_bf16.h>

#define NI 784
#define NH 1024
#define NO 10
#define BATCH 512
#define TSTEPS 100

#define BM 128
#define BN 128
#define BK 16
#define LDT 140   // 140 floats = 560B = 35*16: every k-row 16B-aligned -> all
                  // ds_read_b128 aligned (LDT=132 made odd-k rows 8-mod-16 ->
                  // ~2e7 split-access "conflicts" = half of all reads).
                  // Staging-write banks: 12*skcol mod 32 = {0,16,0,16} -> 2-way free.

typedef __attribute__((ext_vector_type(4))) float floatx4;

__global__ __launch_bounds__(256) void init_ws_kernel(float* __restrict__ p, int n) {
  int i = blockIdx.x * 256 + threadIdx.x;
  if (i < n) p[i] = 0.0f;
}

// C[M,1024] = X[M,784] @ W1[1024,784]^T + b1, fp32.
// Round-0 proven structure (single LDS buffer, 2 barriers/K-tile, register
// prefetch, 80 VGPR) + XCD remap (FETCH 682->231MB proven) + LDT=140 alignment.
// K-accumulation strictly sequential fmaf -> bit-identical to prior rounds.
__global__ __launch_bounds__(256) void sgemm1_kernel(
    const float* __restrict__ X,
    const float* __restrict__ W1,
    const float* __restrict__ b1,
    float* __restrict__ C)
{
  __shared__ __align__(16) float As[BK * LDT];
  __shared__ __align__(16) float Bs[BK * LDT];

  const int tid = threadIdx.x;
  const int tx = tid & 15;            // n-direction group (0..15)
  const int ty = tid >> 4;            // m-direction group (0..15)

  // bijective XCD-aware remap (total blocks = 3200, %8==0)
  const int hb    = blockIdx.y * gridDim.x + blockIdx.x;
  const int chunk = (gridDim.x * gridDim.y) >> 3;
  const int f     = (hb & 7) * chunk + (hb >> 3);
  const int n0 = (f & 7) * BN;
  const int m0 = (f >> 3) * BM;

  const int srow  = tid >> 2;         // 0..63 staging row
  const int skcol = (tid & 3) * 4;    // 0,4,8,12 staging k-offset

  float acc[8][8];
#pragma unroll
  for (int i = 0; i < 8; ++i)
#pragma unroll
    for (int j = 0; j < 8; ++j) acc[i][j] = 0.0f;

  const float* Xs  = X  + (size_t)m0 * NI + skcol;
  const float* W1s = W1 + (size_t)n0 * NI + skcol;

  // prefetch tile 0 into registers
  floatx4 xa0 = *(const floatx4*)&Xs [(size_t)(srow)      * NI];
  floatx4 xa1 = *(const floatx4*)&Xs [(size_t)(64 + srow) * NI];
  floatx4 wq0 = *(const floatx4*)&W1s[(size_t)(srow)      * NI];
  floatx4 wq1 = *(const floatx4*)&W1s[(size_t)(64 + srow) * NI];

  for (int kt = 0; kt < NI / BK; ++kt) {
    __syncthreads();                  // previous tile fully consumed
#pragma unroll
    for (int e = 0; e < 4; ++e) {
      As[(skcol + e) * LDT + srow]      = xa0[e];
      As[(skcol + e) * LDT + 64 + srow] = xa1[e];
      Bs[(skcol + e) * LDT + srow]      = wq0[e];
      Bs[(skcol + e) * LDT + 64 + srow] = wq1[e];
    }
    __syncthreads();

    if (kt + 1 < NI / BK) {           // prefetch next tile; overlaps compute
      const int k0 = (kt + 1) * BK;
      xa0 = *(const floatx4*)&Xs [(size_t)(srow)      * NI + k0];
      xa1 = *(const floatx4*)&Xs [(size_t)(64 + srow) * NI + k0];
      wq0 = *(const floatx4*)&W1s[(size_t)(srow)      * NI + k0];
      wq1 = *(const floatx4*)&W1s[(size_t)(64 + srow) * NI + k0];
    }

#pragma unroll
    for (int k = 0; k < BK; ++k) {
      const floatx4 av0 = *(const floatx4*)&As[k * LDT + ty * 8];
      const floatx4 av1 = *(const floatx4*)&As[k * LDT + ty * 8 + 4];
      const floatx4 bv0 = *(const floatx4*)&Bs[k * LDT + tx * 4];        // 2-way, free
      const floatx4 bv1 = *(const floatx4*)&Bs[k * LDT + 64 + tx * 4];   // 2-way, free
      const float a[8] = {av0[0], av0[1], av0[2], av0[3],
                          av1[0], av1[1], av1[2], av1[3]};
#pragma unroll
      for (int i = 0; i < 8; ++i)
#pragma unroll
        for (int j = 0; j < 4; ++j) {
          acc[i][j]     = fmaf(a[i], bv0[j], acc[i][j]);
          acc[i][4 + j] = fmaf(a[i], bv1[j], acc[i][4 + j]);
        }
    }
  }

#pragma unroll
  for (int i = 0; i < 8; ++i) {
    const int m = m0 + ty * 8 + i;
    floatx4 v0, v1;
#pragma unroll
    for (int j = 0; j < 4; ++j) {
      v0[j] = acc[i][j]     + b1[n0 + tx * 4 + j];
      v1[j] = acc[i][4 + j] + b1[n0 + 64 + tx * 4 + j];
    }
    *(floatx4*)&C[(size_t)m * NH + n0 + tx * 4]      = v0;
    *(floatx4*)&C[(size_t)m * NH + n0 + 64 + tx * 4] = v1;
  }
}

// Fused recurrence: one block per batch row b; all three phases in one kernel
// with spikes + cur2 held in LDS (no global round-trips, 2 fewer launches).
// Phase A == spk1_kernel arithmetic (wave qq == old blockIdx.y), depth-1
// prefetch; phase B == cur2_kernel arithmetic (same tid->h map, same fmaf
// order, same shfl tree, same red[4] sum); phase C == mem2_kernel order.
// -> bit-identical outputs to the proven round-0/2/3 kernels.
__global__ __launch_bounds__(256) void phases_kernel(
    const float* __restrict__ cur1,      // [T,512,1024] fp32
    const float* __restrict__ W2,        // [10,1024]
    const float* __restrict__ b2,        // [10]
    float* __restrict__ out,             // [100*512*10 spk | 512*10 mem2]
    long long out_size)
{
  const int b    = blockIdx.x;
  const int tid  = threadIdx.x;
  const int lane = tid & 63;
  const int wave = tid >> 6;           // == qq == pack group

  __shared__ unsigned long long sp[TSTEPS][16];  // 12.8 KB spike bitpack
  __shared__ float c2s[TSTEPS][NO];              // 4 KB cur2 per t
  __shared__ float red[2][4][NO];

  // ---- phase A: mem1 recurrence, spikes -> LDS ----
  {
    const floatx4* c4 = (const floatx4*)cur1;
    const size_t stride = (size_t)BATCH * (NH / 4);
    const size_t base   = (size_t)b * (NH / 4) + wave * 64 + lane;

    floatx4 m1 = {0.f, 0.f, 0.f, 0.f};
    floatx4 c  = c4[base];

    for (int t = 0; t < TSTEPS; ++t) {
      floatx4 cn = {0.f, 0.f, 0.f, 0.f};
      if (t + 1 < TSTEPS) cn = c4[base + (size_t)(t + 1) * stride];

      unsigned long long bm0 = 0, bm1 = 0, bm2 = 0, bm3 = 0;
#pragma unroll
      for (int j = 0; j < 4; ++j) {
        float mj = m1[j];
        float reset = (mj > 1.0f) ? 1.0f : 0.0f;   // reset from PREVIOUS mem1
        mj = 0.9f * mj + c[j] - reset;
        m1[j] = mj;
        unsigned long long bm = __ballot(mj > 1.0f);
        if (j == 0) bm0 = bm; else if (j == 1) bm1 = bm;
        else if (j == 2) bm2 = bm; else bm3 = bm;
      }

      if (lane < 4) {
        unsigned long long v = bm0;
        if (lane == 1) v = bm1;
        else if (lane == 2) v = bm2;
        else if (lane == 3) v = bm3;
        sp[t][wave * 4 + lane] = v;
      }
      c = cn;
    }
  }
  __syncthreads();

  // ---- phase B: cur2 for all t (identical arithmetic to cur2_kernel) ----
  {
    float w[4][NO];
#pragma unroll
    for (int j = 0; j < 4; ++j)
#pragma unroll
      for (int o = 0; o < NO; ++o)
        w[j][o] = W2[o * NH + tid * 4 + j];

    float bb = 0.0f;
    if (tid < NO) bb = b2[tid];

    for (int t = 0; t < TSTEPS; ++t) {
      const unsigned long long p0 = sp[t][wave * 4 + 0];
      const unsigned long long p1 = sp[t][wave * 4 + 1];
      const unsigned long long p2 = sp[t][wave * 4 + 2];
      const unsigned long long p3 = sp[t][wave * 4 + 3];

      float a[NO];
#pragma unroll
      for (int o = 0; o < NO; ++o) a[o] = 0.0f;

      {
        const float s0 = (float)((p0 >> lane) & 1ULL);
#pragma unroll
        for (int o = 0; o < NO; ++o) a[o] = fmaf(s0, w[0][o], a[o]);
        const float s1 = (float)((p1 >> lane) & 1ULL);
#pragma unroll
        for (int o = 0; o < NO; ++o) a[o] = fmaf(s1, w[1][o], a[o]);
        const float s2 = (float)((p2 >> lane) & 1ULL);
#pragma unroll
        for (int o = 0; o < NO; ++o) a[o] = fmaf(s2, w[2][o], a[o]);
        const float s3 = (float)((p3 >> lane) & 1ULL);
#pragma unroll
        for (int o = 0; o < NO; ++o) a[o] = fmaf(s3, w[3][o], a[o]);
      }

#pragma unroll
      for (int m = 1; m <= 32; m <<= 1)
#pragma unroll
        for (int o = 0; o < NO; ++o) a[o] += __shfl_xor(a[o], m, 64);

      if (lane == 0) {
#pragma unroll
        for (int o = 0; o < NO; ++o) red[t & 1][wave][o] = a[o];
      }
      __syncthreads();                  // parity buffers -> one barrier per t

      if (tid < NO) {
        c2s[t][tid] = red[t & 1][0][tid] + red[t & 1][1][tid]
                    + red[t & 1][2][tid] + red[t & 1][3][tid] + bb;
      }
    }
  }
  __syncthreads();

  // ---- phase C: mem2 recurrence (identical order to mem2_kernel) ----
  if (tid < NO) {
    float m2 = 0.0f;
    for (int t = 0; t < TSTEPS; ++t) {
      float reset2 = (m2 > 1.0f) ? 1.0f : 0.0f;
      m2 = 0.9f * m2 + c2s[t][tid] - reset2;
      float spk2 = (m2 > 1.0f) ? 1.0f : 0.0f;
      long long idx = ((long long)t * BATCH + b) * NO + tid;
      if (idx < out_size) out[idx] = spk2;
    }
    long long idx = (long long)TSTEPS * BATCH * NO + b * NO + tid;
    if (idx < out_size) out[idx] = m2;
  }
}

// Proven fallback recur (chunked path, used only if ws too small for full cur1).
__global__ __launch_bounds__(256) void recur_kernel(
    const float* __restrict__ cur1,
    const float* __restrict__ W2,
    const float* __restrict__ b2,
    float* __restrict__ mem1s,
    float* __restrict__ mem2s,
    float* __restrict__ out,
    long long out_size, int t0, int tc, int last)
{
  const int b    = blockIdx.x;
  const int tid  = threadIdx.x;
  const int lane = tid & 63;
  const int wave = tid >> 6;

  __shared__ float red[4][NO];

  float w[4][NO];
#pragma unroll
  for (int j = 0; j < 4; ++j)
#pragma unroll
    for (int o = 0; o < NO; ++o)
      w[j][o] = W2[o * NH + tid * 4 + j];

  floatx4 m1 = *(const floatx4*)&mem1s[(size_t)b * NH + tid * 4];
  float m2 = 0.0f, bb = 0.0f;
  if (tid < NO) {
    m2 = mem2s[b * NO + tid];
    bb = b2[tid];
  }

  const floatx4* c4 = (const floatx4*)cur1;
  floatx4 c = c4[((size_t)0 * BATCH + b) * (NH / 4) + tid];

  for (int t = 0; t < tc; ++t) {
    floatx4 cn = {0.f, 0.f, 0.f, 0.f};
    if (t + 1 < tc) cn = c4[((size_t)(t + 1) * BATCH + b) * (NH / 4) + tid];

    float a[NO];
#pragma unroll
    for (int o = 0; o < NO; ++o) a[o] = 0.0f;

#pragma unroll
    for (int j = 0; j < 4; ++j) {
      float mj = m1[j];
      float reset = (mj > 1.0f) ? 1.0f : 0.0f;
      mj = 0.9f * mj + c[j] - reset;
      m1[j] = mj;
      float s = (mj > 1.0f) ? 1.0f : 0.0f;
#pragma unroll
      for (int o = 0; o < NO; ++o) a[o] = fmaf(s, w[j][o], a[o]);
    }

#pragma unroll
    for (int m = 1; m <= 32; m <<= 1)
#pragma unroll
      for (int o = 0; o < NO; ++o) a[o] += __shfl_xor(a[o], m, 64);

    if (lane == 0) {
#pragma unroll
      for (int o = 0; o < NO; ++o) red[wave][o] = a[o];
    }
    __syncthreads();

    if (tid < NO) {
      float cur2 = red[0][tid] + red[1][tid] + red[2][tid] + red[3][tid] + bb;
      float reset2 = (m2 > 1.0f) ? 1.0f : 0.0f;
      m2 = 0.9f * m2 + cur2 - reset2;
      float spk2 = (m2 > 1.0f) ? 1.0f : 0.0f;
      long long idx = ((long long)(t0 + t) * BATCH + b) * NO + tid;
      if (idx < out_size) out[idx] = spk2;
    }
    __syncthreads();
    c = cn;
  }

  *(floatx4*)&mem1s[(size_t)b * NH + tid * 4] = m1;
  if (tid < NO) {
    mem2s[b * NO + tid] = m2;
    if (last) {
      long long idx = (long long)TSTEPS * BATCH * NO + b * NO + tid;
      if (idx < out_size) out[idx] = m2;
    }
  }
}

// Proven round-3 fallback (only if workspace is too small for any GEMM path).
__global__ __launch_bounds__(256) void fused_fp32_kernel(
    const float* __restrict__ x,
    const float* __restrict__ W1,
    const float* __restrict__ b1,
    const float* __restrict__ W2,
    const float* __restrict__ b2,
    float* __restrict__ out, long long out_size)
{
  const int b    = blockIdx.x;
  const int tid  = threadIdx.x;
  const int lane = tid & 63;
  const int wave = tid >> 6;

  __shared__ __align__(16) float xs[NI + 4];
  __shared__ float red[4][NO];

  float w[4][NO];
#pragma unroll
  for (int j = 0; j < 4; ++j)
#pragma unroll
    for (int o = 0; o < NO; ++o)
      w[j][o] = W2[o * NH + tid * 4 + j];

  float bias1[4];
#pragma unroll
  for (int j = 0; j < 4; ++j) bias1[j] = b1[tid * 4 + j];

  float m1[4] = {0.f, 0.f, 0.f, 0.f};
  float m2 = 0.0f, bb = 0.0f;
  if (tid < NO) bb = b2[tid];

  for (int t = 0; t < TSTEPS; ++t) {
    if (tid < 196)
      *(floatx4*)&xs[tid * 4] = *(const floatx4*)&x[((size_t)t * BATCH + b) * NI + tid * 4];
    __syncthreads();

    float a[NO];
#pragma unroll
    for (int o = 0; o < NO; ++o) a[o] = 0.0f;

#pragma unroll
    for (int j = 0; j < 4; ++j) {
      const float* wr = W1 + (size_t)(tid * 4 + j) * NI;
      float dot = 0.0f;
      for (int cch = 0; cch < 196; ++cch) {
        floatx4 wv = *(const floatx4*)&wr[cch * 4];
        floatx4 xv = *(const floatx4*)&xs[cch * 4];
#pragma unroll
        for (int e = 0; e < 4; ++e) dot = fmaf(wv[e], xv[e], dot);
      }
      float cur = dot + bias1[j];
      float mj = m1[j];
      float reset = (mj > 1.0f) ? 1.0f : 0.0f;
      mj = 0.9f * mj + cur - reset;
      m1[j] = mj;
      float s = (mj > 1.0f) ? 1.0f : 0.0f;
#pragma unroll
      for (int o = 0; o < NO; ++o) a[o] = fmaf(s, w[j][o], a[o]);
    }

#pragma unroll
    for (int m = 1; m <= 32; m <<= 1)
#pragma unroll
      for (int o = 0; o < NO; ++o) a[o] += __shfl_xor(a[o], m, 64);

    if (lane == 0) {
#pragma unroll
      for (int o = 0; o < NO; ++o) red[wave][o] = a[o];
    }
    __syncthreads();

    if (tid < NO) {
      float cur2 = red[0][tid] + red[1][tid] + red[2][tid] + red[3][tid] + bb;
      float reset2 = (m2 > 1.0f) ? 1.0f : 0.0f;
      m2 = 0.9f * m2 + cur2 - reset2;
      float spk2 = (m2 > 1.0f) ? 1.0f : 0.0f;
      long long idx = ((long long)t * BATCH + b) * NO + tid;
      if (idx < out_size) out[idx] = spk2;
    }
    __syncthreads();
  }

  if (tid < NO) {
    long long idx = (long long)TSTEPS * BATCH * NO + b * NO + tid;
    if (idx < out_size) out[idx] = m2;
  }
}

extern "C" void kernel_launch(void* const* d_in, const int* in_sizes, int n_in,
                              void* d_out, int out_size, void* d_ws, size_t ws_size,
                              hipStream_t stream) {
  const float* x  = (const float*)d_in[0];
  const float* W1 = (const float*)d_in[1];
  const float* b1 = (const float*)d_in[2];
  const float* W2 = (const float*)d_in[3];
  const float* b2 = (const float*)d_in[4];
  float* out = (float*)d_out;

  char* ws = (char*)d_ws;

  // ---------- preferred path: full-T GEMM + fused phases ----------
  const size_t cur1_bytes = (size_t)TSTEPS * BATCH * NH * 4;   // 200 MB

  if (d_ws != nullptr && ws_size >= cur1_bytes) {
    float* cur1 = (float*)ws;

    dim3 g(NH / BN, (TSTEPS * BATCH) / BM);        // (8, 400)
    sgemm1_kernel<<<g, 256, 0, stream>>>(x, W1, b1, cur1);
    phases_kernel<<<BATCH, 256, 0, stream>>>(cur1, W2, b2, out,
                                             (long long)out_size);
    return;
  }

  // ---------- fallback: proven chunked GEMM + recur path ----------
  const size_t mem1_bytes = (size_t)BATCH * NH * 4;
  const size_t mem2_bytes = (size_t)BATCH * NO * 4;
  size_t fixed = (mem1_bytes + mem2_bytes + 255) & ~(size_t)255;
  const size_t per_step = (size_t)BATCH * NH * 4;   // 2 MB fp32 per timestep

  if (d_ws == nullptr || ws_size < fixed + per_step) {
    fused_fp32_kernel<<<BATCH, 256, 0, stream>>>(x, W1, b1, W2, b2, out,
                                                 (long long)out_size);
    return;
  }

  float* mem1s = (float*)ws;
  float* mem2s = (float*)(ws + mem1_bytes);
  float* cur1  = (float*)(ws + fixed);

  int Tc = (int)((ws_size - fixed) / per_step);
  if (Tc > TSTEPS) Tc = TSTEPS;

  const int nInit = BATCH * NH + BATCH * NO;
  init_ws_kernel<<<(nInit + 255) / 256, 256, 0, stream>>>((float*)ws, nInit);

  for (int t0 = 0; t0 < TSTEPS; t0 += Tc) {
    const int tc = (TSTEPS - t0 < Tc) ? (TSTEPS - t0) : Tc;
    const int M = tc * BATCH;                    // multiple of 128
    dim3 g(NH / BN, M / BM);
    sgemm1_kernel<<<g, 256, 0, stream>>>(x + (size_t)t0 * BATCH * NI, W1, b1, cur1);
    recur_kernel<<<BATCH, 256, 0, stream>>>(cur1, W2, b2, mem1s, mem2s, out,
                                            (long long)out_size, t0, tc,
                                            (t0 + tc >= TSTEPS) ? 1 : 0);
  }
}